// Round 1
// baseline (580.040 us; speedup 1.0000x reference)
//
#include <hip/hip_runtime.h>

// Problem constants (fixed by reference file)
#define N_TRUCK 100000
#define BLK 256

// ---------------- workspace layout (bytes) ----------------
// zeroed region (memset each launch):
//   cnt_t   : int  [N_TRUCK]             @ 0
//   sumdis  : float[N_TRUCK]             @ 400000
//   degw_c  : float[N_CAR]               @ 800000
//   y4      : float[4*N_CAR]             @ 1200000   (16B aligned)
// zero region ends at 2800000
//   dis_t   : float[N_TRUCK]             @ 2800000
//   dis_c   : float[N_CAR]               @ 3200000
//   s_t     : float[N_TRUCK]             @ 3600000
//   G       : float[36]                  @ 4000000

__global__ void k_deg(const int* __restrict__ tcol, const int* __restrict__ ccol,
                      const float* __restrict__ ew, int E_,
                      int* __restrict__ cnt_t, float* __restrict__ degw_c) {
    int i = blockIdx.x * blockDim.x + threadIdx.x;
    if (i >= E_) return;
    atomicAdd(&cnt_t[tcol[i]], 1);
    atomicAdd(&degw_c[ccol[i]], ew[i]);
}

__global__ void k_dis(const int* __restrict__ cnt_t, const float* __restrict__ degw_c,
                      float* __restrict__ dis_t, float* __restrict__ dis_c,
                      int nt, int nc) {
    int i = blockIdx.x * blockDim.x + threadIdx.x;
    if (i < nt) dis_t[i] = rsqrtf((float)cnt_t[i] + 1.0f);
    if (i < nc) dis_c[i] = rsqrtf(degw_c[i] + 1.0f);
}

__global__ void k_scat(const int* __restrict__ trow, const int* __restrict__ tcol,
                       const int* __restrict__ crow, const int* __restrict__ ccol,
                       const float* __restrict__ ew, int E_,
                       const float* __restrict__ dis_t, const float* __restrict__ dis_c,
                       const float* __restrict__ x_car,
                       float* __restrict__ sumdis, float* __restrict__ y4) {
    int i = blockIdx.x * blockDim.x + threadIdx.x;
    if (i >= E_) return;
    // truck: sumdis[col] += dis_t[row]
    atomicAdd(&sumdis[tcol[i]], dis_t[trow[i]]);
    // car: y4[col] += norm * x_car[row]
    int r = crow[i], c = ccol[i];
    float nrm = dis_c[r] * ew[i] * dis_c[c];
    atomicAdd(&y4[c * 4 + 0], nrm * x_car[r * 3 + 0]);
    atomicAdd(&y4[c * 4 + 1], nrm * x_car[r * 3 + 1]);
    atomicAdd(&y4[c * 4 + 2], nrm * x_car[r * 3 + 2]);
}

__global__ void k_fin(int nt, int nc,
                      const float* __restrict__ dis_t, const float* __restrict__ sumdis,
                      float* __restrict__ s_t,
                      const float* __restrict__ dis_c, const float* __restrict__ x_car,
                      float* __restrict__ y4) {
    int i = blockIdx.x * blockDim.x + threadIdx.x;
    if (i < nt) {
        float d = dis_t[i];
        s_t[i] = d * sumdis[i] + d * d;
    }
    if (i < nc) {
        float d2 = dis_c[i] * dis_c[i];
        y4[i * 4 + 0] += d2 * x_car[i * 3 + 0];
        y4[i * 4 + 1] += d2 * x_car[i * 3 + 1];
        y4[i * 4 + 2] += d2 * x_car[i * 3 + 2];
        y4[i * 4 + 3] = 1.0f;
    }
}

// G[a][b] = sum_h M[a,h]*M[b,h]*wlin[h], M rows = {W_truck, b_truck, Wc0, Wc1, Wc2, b_car}
__global__ void k_G(const float* __restrict__ Wt, const float* __restrict__ bt,
                    const float* __restrict__ Wc, const float* __restrict__ bc,
                    const float* __restrict__ wlin, float* __restrict__ G) {
    int l = threadIdx.x;  // 64 threads, 1 wave
    float acc[21];
#pragma unroll
    for (int k = 0; k < 21; k++) acc[k] = 0.0f;
    for (int h = l; h < 128; h += 64) {
        float m[6] = {Wt[h], bt[h], Wc[h], Wc[128 + h], Wc[256 + h], bc[h]};
        float w = wlin[h];
        int k = 0;
#pragma unroll
        for (int a = 0; a < 6; a++)
#pragma unroll
            for (int b = a; b < 6; b++)
                acc[k++] += m[a] * m[b] * w;
    }
    int k = 0;
#pragma unroll
    for (int a = 0; a < 6; a++)
#pragma unroll
        for (int b = a; b < 6; b++) {
            float v = acc[k++];
#pragma unroll
            for (int off = 32; off; off >>= 1) v += __shfl_down(v, off);
            if (l == 0) {
                G[a * 6 + b] = v;
                G[b * 6 + a] = v;
            }
        }
}

__device__ __forceinline__ void load_z(int i, const float* __restrict__ s_t,
                                       const float4* __restrict__ y4, float z[6]) {
    if (i < N_TRUCK) {
        z[0] = s_t[i]; z[1] = 1.0f; z[2] = 0.0f; z[3] = 0.0f; z[4] = 0.0f; z[5] = 0.0f;
    } else {
        float4 y = y4[i - N_TRUCK];
        z[0] = 0.0f; z[1] = 0.0f; z[2] = y.x; z[3] = y.y; z[4] = y.z; z[5] = 1.0f;
    }
}

__global__ void k_pairs(const int* __restrict__ src, const int* __restrict__ dst, int P_,
                        const float* __restrict__ s_t, const float4* __restrict__ y4,
                        const float* __restrict__ G, const float* __restrict__ b_lin,
                        float* __restrict__ out) {
    int p = blockIdx.x * blockDim.x + threadIdx.x;
    if (p >= P_) return;
    float zs[6], zd[6];
    load_z(src[p], s_t, y4, zs);
    load_z(dst[p], s_t, y4, zd);
    float acc = 0.0f;
#pragma unroll
    for (int a = 0; a < 6; a++) {
        float g = 0.0f;
#pragma unroll
        for (int b = 0; b < 6; b++) g = fmaf(G[a * 6 + b], zd[b], g);
        acc = fmaf(zs[a], g, acc);
    }
    out[p] = acc + b_lin[0];
}

extern "C" void kernel_launch(void* const* d_in, const int* in_sizes, int n_in,
                              void* d_out, int out_size, void* d_ws, size_t ws_size,
                              hipStream_t stream) {
    const float* x_car  = (const float*)d_in[0];
    const int*   ei_t   = (const int*)d_in[1];
    const int*   ei_c   = (const int*)d_in[2];
    const float* ew_c   = (const float*)d_in[3];
    const int*   src    = (const int*)d_in[4];
    const int*   dst    = (const int*)d_in[5];
    // d_in[6] = n_truck scalar (device) — using compile-time N_TRUCK
    const float* W_t    = (const float*)d_in[7];
    const float* b_t    = (const float*)d_in[8];
    const float* W_c    = (const float*)d_in[9];
    const float* b_c    = (const float*)d_in[10];
    const float* W_lin  = (const float*)d_in[11];
    const float* b_lin  = (const float*)d_in[12];
    float* out = (float*)d_out;

    const int NC = in_sizes[0] / 3;       // 100000
    const int E_ = in_sizes[1] / 2;       // 1600000
    const int P_ = in_sizes[4];           // 200000

    char* ws = (char*)d_ws;
    int*   cnt_t  = (int*)(ws + 0);
    float* sumdis = (float*)(ws + 400000);
    float* degw_c = (float*)(ws + 800000);
    float* y4     = (float*)(ws + 1200000);
    float* dis_t  = (float*)(ws + 2800000);
    float* dis_c  = (float*)(ws + 3200000);
    float* s_t    = (float*)(ws + 3600000);
    float* G      = (float*)(ws + 4000000);

    // zero the atomic accumulators (cnt_t, sumdis, degw_c, y4)
    hipMemsetAsync(ws, 0, 2800000, stream);

    const int* trow = ei_t;        const int* tcol = ei_t + E_;
    const int* crow = ei_c;        const int* ccol = ei_c + E_;

    int gE = (E_ + BLK - 1) / BLK;
    int gN = (N_TRUCK > NC ? N_TRUCK : NC + BLK - 1) / BLK + 1;  // cover both
    gN = ((N_TRUCK > NC ? N_TRUCK : NC) + BLK - 1) / BLK;
    int gP = (P_ + BLK - 1) / BLK;

    k_deg<<<gE, BLK, 0, stream>>>(tcol, ccol, ew_c, E_, cnt_t, degw_c);
    k_dis<<<gN, BLK, 0, stream>>>(cnt_t, degw_c, dis_t, dis_c, N_TRUCK, NC);
    k_scat<<<gE, BLK, 0, stream>>>(trow, tcol, crow, ccol, ew_c, E_,
                                   dis_t, dis_c, x_car, sumdis, y4);
    k_fin<<<gN, BLK, 0, stream>>>(N_TRUCK, NC, dis_t, sumdis, s_t, dis_c, x_car, y4);
    k_G<<<1, 64, 0, stream>>>(W_t, b_t, W_c, b_c, W_lin, G);
    k_pairs<<<gP, BLK, 0, stream>>>(src, dst, P_, s_t, (const float4*)y4, G, b_lin, out);
}

// Round 2
// 280.533 us; speedup vs baseline: 2.0676x; 2.0676x over previous
//
#include <hip/hip_runtime.h>

// Problem constants (fixed by reference file)
#define N_TRUCK 100000
#define BLK 256
#define NB 512          // buckets per graph
#define NPB 196         // nodes per bucket: ceil(100000/512)
#define PLACE_BLOCKS 128

// ---------------- NEW ws layout (bytes) ----------------
//      0 : histT[512] int   (zeroed: memset [0,4096))
//   2048 : histC[512] int
//   4096 : cursorT[512] int
//   6144 : cursorC[512] int
//   8192 : baseT[513] int
//  12288 : baseC[513] int
//  16384 : G[36] float
//  65536 : dis_t[100000] f32
// 465536 : dis_c[100000] f32
// 865536 : s_t [100000] f32
// 1265536: y4  [4*100000] f32 (16B aligned)
// 2865536: pT  [E] u32    ((localcol<<24)|row)
// 9265536: pC  [E] u32
// 15665536: ewS[E] f32    (bucket-sorted car edge weights)
// total: 22065536
#define WS_NEED 22065536ULL

// ============ new path kernels ============

__global__ void k_hist(const int* __restrict__ tcol, const int* __restrict__ ccol, int E_,
                       int* __restrict__ histT, int* __restrict__ histC) {
    __shared__ int hT[NB], hC[NB];
    for (int k = threadIdx.x; k < NB; k += blockDim.x) { hT[k] = 0; hC[k] = 0; }
    __syncthreads();
    for (int j = blockIdx.x * blockDim.x + threadIdx.x; j < E_; j += gridDim.x * blockDim.x) {
        atomicAdd(&hT[tcol[j] / NPB], 1);
        atomicAdd(&hC[ccol[j] / NPB], 1);
    }
    __syncthreads();
    for (int k = threadIdx.x; k < NB; k += blockDim.x) {
        if (hT[k]) atomicAdd(&histT[k], hT[k]);
        if (hC[k]) atomicAdd(&histC[k], hC[k]);
    }
}

__global__ void k_scan(const int* __restrict__ histT, const int* __restrict__ histC,
                       int* __restrict__ baseT, int* __restrict__ baseC,
                       int* __restrict__ curT, int* __restrict__ curC) {
    __shared__ int s[NB];
    int t = threadIdx.x;
    // truck
    int v = histT[t];
    s[t] = v; __syncthreads();
    for (int off = 1; off < NB; off <<= 1) {
        int x = (t >= off) ? s[t - off] : 0;
        __syncthreads();
        s[t] += x;
        __syncthreads();
    }
    int excl = s[t] - v;
    baseT[t] = excl; curT[t] = excl;
    if (t == NB - 1) baseT[NB] = s[t];
    __syncthreads();
    // car
    v = histC[t];
    s[t] = v; __syncthreads();
    for (int off = 1; off < NB; off <<= 1) {
        int x = (t >= off) ? s[t - off] : 0;
        __syncthreads();
        s[t] += x;
        __syncthreads();
    }
    excl = s[t] - v;
    baseC[t] = excl; curC[t] = excl;
    if (t == NB - 1) baseC[NB] = s[t];
}

__global__ void k_place(const int* __restrict__ trow, const int* __restrict__ tcol,
                        const int* __restrict__ crow, const int* __restrict__ ccol,
                        const float* __restrict__ ew, int E_,
                        int* __restrict__ curT, int* __restrict__ curC,
                        unsigned* __restrict__ pT, unsigned* __restrict__ pC,
                        float* __restrict__ ewS) {
    __shared__ int hT[NB], hC[NB];
    int chunk = (E_ + gridDim.x - 1) / gridDim.x;
    int s0 = blockIdx.x * chunk;
    int s1 = min(E_, s0 + chunk);
    for (int k = threadIdx.x; k < NB; k += blockDim.x) { hT[k] = 0; hC[k] = 0; }
    __syncthreads();
    for (int j = s0 + threadIdx.x; j < s1; j += blockDim.x) {
        atomicAdd(&hT[tcol[j] / NPB], 1);
        atomicAdd(&hC[ccol[j] / NPB], 1);
    }
    __syncthreads();
    for (int k = threadIdx.x; k < NB; k += blockDim.x) {
        hT[k] = hT[k] ? atomicAdd(&curT[k], hT[k]) : 0;  // hT becomes block base / sub-cursor
        hC[k] = hC[k] ? atomicAdd(&curC[k], hC[k]) : 0;
    }
    __syncthreads();
    for (int j = s0 + threadIdx.x; j < s1; j += blockDim.x) {
        int tc = tcol[j];
        int k = tc / NPB;
        int pos = atomicAdd(&hT[k], 1);
        pT[pos] = ((unsigned)(tc - k * NPB) << 24) | (unsigned)trow[j];
        int cc = ccol[j];
        int k2 = cc / NPB;
        int p2 = atomicAdd(&hC[k2], 1);
        pC[p2] = ((unsigned)(cc - k2 * NPB) << 24) | (unsigned)crow[j];
        ewS[p2] = ew[j];
    }
}

// one block per bucket: blocks [0,NB) truck, [NB,2NB) car
__global__ void k_deg2(const unsigned* __restrict__ pT, const unsigned* __restrict__ pC,
                       const float* __restrict__ ewS,
                       const int* __restrict__ baseT, const int* __restrict__ baseC,
                       float* __restrict__ dis_t, float* __restrict__ dis_c, int ntot) {
    __shared__ float acc[NPB];
    int b = blockIdx.x;
    bool car = b >= NB;
    int bk = car ? b - NB : b;
    const int* base = car ? baseC : baseT;
    int s0 = base[bk], s1 = base[bk + 1];
    for (int k = threadIdx.x; k < NPB; k += blockDim.x) acc[k] = 0.0f;
    __syncthreads();
    if (car) {
        for (int j = s0 + threadIdx.x; j < s1; j += blockDim.x)
            atomicAdd(&acc[pC[j] >> 24], ewS[j]);
    } else {
        for (int j = s0 + threadIdx.x; j < s1; j += blockDim.x)
            atomicAdd(&acc[pT[j] >> 24], 1.0f);
    }
    __syncthreads();
    float* dis = car ? dis_c : dis_t;
    for (int n = threadIdx.x; n < NPB; n += blockDim.x) {
        int node = bk * NPB + n;
        if (node < ntot) dis[node] = rsqrtf(acc[n] + 1.0f);
    }
}

__global__ void k_agg(const unsigned* __restrict__ pT, const unsigned* __restrict__ pC,
                      const float* __restrict__ ewS,
                      const int* __restrict__ baseT, const int* __restrict__ baseC,
                      const float* __restrict__ dis_t, const float* __restrict__ dis_c,
                      const float* __restrict__ x_car,
                      float* __restrict__ s_t, float4* __restrict__ y4, int ntot) {
    int b = blockIdx.x;
    if (b < NB) {
        __shared__ float sacc[NPB];
        int s0 = baseT[b], s1 = baseT[b + 1];
        for (int k = threadIdx.x; k < NPB; k += blockDim.x) sacc[k] = 0.0f;
        __syncthreads();
        for (int j = s0 + threadIdx.x; j < s1; j += blockDim.x) {
            unsigned v = pT[j];
            atomicAdd(&sacc[v >> 24], dis_t[v & 0x00FFFFFFu]);
        }
        __syncthreads();
        for (int n = threadIdx.x; n < NPB; n += blockDim.x) {
            int node = b * NPB + n;
            if (node < ntot) {
                float d = dis_t[node];
                s_t[node] = fmaf(d, sacc[n], d * d);
            }
        }
    } else {
        int bk = b - NB;
        __shared__ float y[NPB * 5];   // stride 5: avoid stride-4 bank aliasing
        __shared__ float dcl[NPB];
        int s0 = baseC[bk], s1 = baseC[bk + 1];
        for (int k = threadIdx.x; k < NPB * 5; k += blockDim.x) y[k] = 0.0f;
        for (int k = threadIdx.x; k < NPB; k += blockDim.x) {
            int node = bk * NPB + k;
            dcl[k] = (node < ntot) ? dis_c[node] : 0.0f;
        }
        __syncthreads();
        for (int j = s0 + threadIdx.x; j < s1; j += blockDim.x) {
            unsigned v = pC[j];
            int r = (int)(v & 0x00FFFFFFu);
            int lc = (int)(v >> 24);
            float nrm = dis_c[r] * ewS[j] * dcl[lc];
            const float* xr = &x_car[3 * r];
            atomicAdd(&y[lc * 5 + 0], nrm * xr[0]);
            atomicAdd(&y[lc * 5 + 1], nrm * xr[1]);
            atomicAdd(&y[lc * 5 + 2], nrm * xr[2]);
        }
        __syncthreads();
        for (int n = threadIdx.x; n < NPB; n += blockDim.x) {
            int node = bk * NPB + n;
            if (node < ntot) {
                float d2 = dcl[n] * dcl[n];
                const float* xn = &x_car[3 * node];
                y4[node] = make_float4(fmaf(d2, xn[0], y[n * 5 + 0]),
                                       fmaf(d2, xn[1], y[n * 5 + 1]),
                                       fmaf(d2, xn[2], y[n * 5 + 2]), 1.0f);
            }
        }
    }
}

// ============ shared epilogue kernels ============

// G[a][b] = sum_h M[a,h]*M[b,h]*wlin[h], M rows = {W_truck, b_truck, Wc0, Wc1, Wc2, b_car}
__global__ void k_G(const float* __restrict__ Wt, const float* __restrict__ bt,
                    const float* __restrict__ Wc, const float* __restrict__ bc,
                    const float* __restrict__ wlin, float* __restrict__ G) {
    int l = threadIdx.x;  // 64 threads, 1 wave
    float acc[21];
#pragma unroll
    for (int k = 0; k < 21; k++) acc[k] = 0.0f;
    for (int h = l; h < 128; h += 64) {
        float m[6] = {Wt[h], bt[h], Wc[h], Wc[128 + h], Wc[256 + h], bc[h]};
        float w = wlin[h];
        int k = 0;
#pragma unroll
        for (int a = 0; a < 6; a++)
#pragma unroll
            for (int b = a; b < 6; b++)
                acc[k++] += m[a] * m[b] * w;
    }
    int k = 0;
#pragma unroll
    for (int a = 0; a < 6; a++)
#pragma unroll
        for (int b = a; b < 6; b++) {
            float v = acc[k++];
#pragma unroll
            for (int off = 32; off; off >>= 1) v += __shfl_down(v, off);
            if (l == 0) {
                G[a * 6 + b] = v;
                G[b * 6 + a] = v;
            }
        }
}

__device__ __forceinline__ void load_z(int i, const float* __restrict__ s_t,
                                       const float4* __restrict__ y4, float z[6]) {
    if (i < N_TRUCK) {
        z[0] = s_t[i]; z[1] = 1.0f; z[2] = 0.0f; z[3] = 0.0f; z[4] = 0.0f; z[5] = 0.0f;
    } else {
        float4 y = y4[i - N_TRUCK];
        z[0] = 0.0f; z[1] = 0.0f; z[2] = y.x; z[3] = y.y; z[4] = y.z; z[5] = 1.0f;
    }
}

__global__ void k_pairs(const int* __restrict__ src, const int* __restrict__ dst, int P_,
                        const float* __restrict__ s_t, const float4* __restrict__ y4,
                        const float* __restrict__ G, const float* __restrict__ b_lin,
                        float* __restrict__ out) {
    int p = blockIdx.x * blockDim.x + threadIdx.x;
    if (p >= P_) return;
    float zs[6], zd[6];
    load_z(src[p], s_t, y4, zs);
    load_z(dst[p], s_t, y4, zd);
    float acc = 0.0f;
#pragma unroll
    for (int a = 0; a < 6; a++) {
        float g = 0.0f;
#pragma unroll
        for (int b = 0; b < 6; b++) g = fmaf(G[a * 6 + b], zd[b], g);
        acc = fmaf(zs[a], g, acc);
    }
    out[p] = acc + b_lin[0];
}

// ============ fallback (old atomic path) kernels ============

__global__ void k_deg(const int* __restrict__ tcol, const int* __restrict__ ccol,
                      const float* __restrict__ ew, int E_,
                      int* __restrict__ cnt_t, float* __restrict__ degw_c) {
    int i = blockIdx.x * blockDim.x + threadIdx.x;
    if (i >= E_) return;
    atomicAdd(&cnt_t[tcol[i]], 1);
    atomicAdd(&degw_c[ccol[i]], ew[i]);
}

__global__ void k_dis(const int* __restrict__ cnt_t, const float* __restrict__ degw_c,
                      float* __restrict__ dis_t, float* __restrict__ dis_c,
                      int nt, int nc) {
    int i = blockIdx.x * blockDim.x + threadIdx.x;
    if (i < nt) dis_t[i] = rsqrtf((float)cnt_t[i] + 1.0f);
    if (i < nc) dis_c[i] = rsqrtf(degw_c[i] + 1.0f);
}

__global__ void k_scat(const int* __restrict__ trow, const int* __restrict__ tcol,
                       const int* __restrict__ crow, const int* __restrict__ ccol,
                       const float* __restrict__ ew, int E_,
                       const float* __restrict__ dis_t, const float* __restrict__ dis_c,
                       const float* __restrict__ x_car,
                       float* __restrict__ sumdis, float* __restrict__ y4) {
    int i = blockIdx.x * blockDim.x + threadIdx.x;
    if (i >= E_) return;
    atomicAdd(&sumdis[tcol[i]], dis_t[trow[i]]);
    int r = crow[i], c = ccol[i];
    float nrm = dis_c[r] * ew[i] * dis_c[c];
    atomicAdd(&y4[c * 4 + 0], nrm * x_car[r * 3 + 0]);
    atomicAdd(&y4[c * 4 + 1], nrm * x_car[r * 3 + 1]);
    atomicAdd(&y4[c * 4 + 2], nrm * x_car[r * 3 + 2]);
}

__global__ void k_fin(int nt, int nc,
                      const float* __restrict__ dis_t, const float* __restrict__ sumdis,
                      float* __restrict__ s_t,
                      const float* __restrict__ dis_c, const float* __restrict__ x_car,
                      float* __restrict__ y4) {
    int i = blockIdx.x * blockDim.x + threadIdx.x;
    if (i < nt) {
        float d = dis_t[i];
        s_t[i] = d * sumdis[i] + d * d;
    }
    if (i < nc) {
        float d2 = dis_c[i] * dis_c[i];
        y4[i * 4 + 0] += d2 * x_car[i * 3 + 0];
        y4[i * 4 + 1] += d2 * x_car[i * 3 + 1];
        y4[i * 4 + 2] += d2 * x_car[i * 3 + 2];
        y4[i * 4 + 3] = 1.0f;
    }
}

// ============ launch ============

extern "C" void kernel_launch(void* const* d_in, const int* in_sizes, int n_in,
                              void* d_out, int out_size, void* d_ws, size_t ws_size,
                              hipStream_t stream) {
    const float* x_car  = (const float*)d_in[0];
    const int*   ei_t   = (const int*)d_in[1];
    const int*   ei_c   = (const int*)d_in[2];
    const float* ew_c   = (const float*)d_in[3];
    const int*   src    = (const int*)d_in[4];
    const int*   dst    = (const int*)d_in[5];
    const float* W_t    = (const float*)d_in[7];
    const float* b_t    = (const float*)d_in[8];
    const float* W_c    = (const float*)d_in[9];
    const float* b_c    = (const float*)d_in[10];
    const float* W_lin  = (const float*)d_in[11];
    const float* b_lin  = (const float*)d_in[12];
    float* out = (float*)d_out;

    const int NC = in_sizes[0] / 3;   // 100000
    const int E_ = in_sizes[1] / 2;   // 1600000
    const int P_ = in_sizes[4];       // 200000

    const int* trow = ei_t;  const int* tcol = ei_t + E_;
    const int* crow = ei_c;  const int* ccol = ei_c + E_;

    char* ws = (char*)d_ws;
    int gP = (P_ + BLK - 1) / BLK;

    if (ws_size >= WS_NEED) {
        int*      histT = (int*)(ws + 0);
        int*      histC = (int*)(ws + 2048);
        int*      curT  = (int*)(ws + 4096);
        int*      curC  = (int*)(ws + 6144);
        int*      baseT = (int*)(ws + 8192);
        int*      baseC = (int*)(ws + 12288);
        float*    G     = (float*)(ws + 16384);
        float*    dis_t = (float*)(ws + 65536);
        float*    dis_c = (float*)(ws + 465536);
        float*    s_t   = (float*)(ws + 865536);
        float*    y4    = (float*)(ws + 1265536);
        unsigned* pT    = (unsigned*)(ws + 2865536);
        unsigned* pC    = (unsigned*)(ws + 9265536);
        float*    ewS   = (float*)(ws + 15665536);

        hipMemsetAsync(ws, 0, 4096, stream);  // histT + histC
        k_hist<<<PLACE_BLOCKS, BLK, 0, stream>>>(tcol, ccol, E_, histT, histC);
        k_scan<<<1, NB, 0, stream>>>(histT, histC, baseT, baseC, curT, curC);
        k_place<<<PLACE_BLOCKS, BLK, 0, stream>>>(trow, tcol, crow, ccol, ew_c, E_,
                                                  curT, curC, pT, pC, ewS);
        k_deg2<<<2 * NB, BLK, 0, stream>>>(pT, pC, ewS, baseT, baseC, dis_t, dis_c, NC);
        k_G<<<1, 64, 0, stream>>>(W_t, b_t, W_c, b_c, W_lin, G);
        k_agg<<<2 * NB, BLK, 0, stream>>>(pT, pC, ewS, baseT, baseC, dis_t, dis_c,
                                          x_car, s_t, (float4*)y4, NC);
        k_pairs<<<gP, BLK, 0, stream>>>(src, dst, P_, s_t, (const float4*)y4, G, b_lin, out);
    } else {
        // fallback: previous (passing) global-atomic path
        int*   cnt_t  = (int*)(ws + 0);
        float* sumdis = (float*)(ws + 400000);
        float* degw_c = (float*)(ws + 800000);
        float* y4     = (float*)(ws + 1200000);
        float* dis_t  = (float*)(ws + 2800000);
        float* dis_c  = (float*)(ws + 3200000);
        float* s_t    = (float*)(ws + 3600000);
        float* G      = (float*)(ws + 4000000);

        hipMemsetAsync(ws, 0, 2800000, stream);
        int gE = (E_ + BLK - 1) / BLK;
        int gN = ((N_TRUCK > NC ? N_TRUCK : NC) + BLK - 1) / BLK;
        k_deg<<<gE, BLK, 0, stream>>>(tcol, ccol, ew_c, E_, cnt_t, degw_c);
        k_dis<<<gN, BLK, 0, stream>>>(cnt_t, degw_c, dis_t, dis_c, N_TRUCK, NC);
        k_scat<<<gE, BLK, 0, stream>>>(trow, tcol, crow, ccol, ew_c, E_,
                                       dis_t, dis_c, x_car, sumdis, y4);
        k_fin<<<gN, BLK, 0, stream>>>(N_TRUCK, NC, dis_t, sumdis, s_t, dis_c, x_car, y4);
        k_G<<<1, 64, 0, stream>>>(W_t, b_t, W_c, b_c, W_lin, G);
        k_pairs<<<gP, BLK, 0, stream>>>(src, dst, P_, s_t, (const float4*)y4, G, b_lin, out);
    }
}

// Round 3
// 214.761 us; speedup vs baseline: 2.7009x; 1.3063x over previous
//
#include <hip/hip_runtime.h>

// Problem constants (fixed by reference file)
#define N_TRUCK 100000
#define BLK 256
#define NB 256           // buckets per graph
#define NPB 391          // nodes per bucket: ceil(100000/256)
#define PB 1024          // placer/hist blocks (chunks)
#define ROW_MASK 0x1FFFFu
#define LC_SHIFT 17

// ---------------- ws layout (bytes) ----------------
// cntT i32[NB][PB] @ 0        (1048576)   } dead after k_place (become loff in-place)
// cntC i32[NB][PB] @ 1048576  (1048576)   }
// overlay (written only after k_place):
//   dis_t @ 0        (400000)
//   dis_c @ 400000   (400000)
//   s_t   @ 800000   (400000)
//   y4    @ 1200000  (1600000)  ends 2800000
// baseT @ 2800000 (1028)   baseC @ 2801028 (1028)   G @ 2802056 (144)
// totT  @ 2802200 (1024)   totC  @ 2803224 (1024)
// pT  u32[E] @ 2804352 (6400000)
// pC8 u64[E] @ 9204352 (12800000)  ends 22004352
#define WS_NEED 22004352ULL

// ============ sort-path kernels ============

// PB blocks: per-chunk LDS histogram -> cnt[k][b]
__global__ void k_hist(const int* __restrict__ tcol, const int* __restrict__ ccol, int E_,
                       int* __restrict__ cntT, int* __restrict__ cntC) {
    __shared__ int hT[NB], hC[NB];
    int b = blockIdx.x;
    int chunk = (E_ + PB - 1) / PB;
    int s0 = b * chunk, s1 = min(E_, s0 + chunk);
    for (int k = threadIdx.x; k < NB; k += blockDim.x) { hT[k] = 0; hC[k] = 0; }
    __syncthreads();
    for (int j = s0 + threadIdx.x; j < s1; j += blockDim.x) {
        atomicAdd(&hT[tcol[j] / NPB], 1);
        atomicAdd(&hC[ccol[j] / NPB], 1);
    }
    __syncthreads();
    for (int k = threadIdx.x; k < NB; k += blockDim.x) {
        cntT[k * PB + b] = hT[k];
        cntC[k * PB + b] = hC[k];
    }
}

// 2*NB blocks: exclusive scan of cnt[k][0..PB) IN PLACE, bucket total -> tot[k]
__global__ void k_scanB(int* __restrict__ cntT, int* __restrict__ cntC,
                        int* __restrict__ totT, int* __restrict__ totC) {
    __shared__ int wsum[256];
    int g = blockIdx.x;
    bool car = g >= NB;
    int k = car ? g - NB : g;
    int* cnt = (car ? cntC : cntT) + k * PB;
    int* tot = car ? totC : totT;
    int t = threadIdx.x;                 // 256 threads, 4 elems each
    int4 a = ((int4*)cnt)[t];
    int local = a.x + a.y + a.z + a.w;
    wsum[t] = local;
    __syncthreads();
    for (int off = 1; off < 256; off <<= 1) {
        int x = (t >= off) ? wsum[t - off] : 0;
        __syncthreads();
        wsum[t] += x;
        __syncthreads();
    }
    int run = wsum[t] - local;           // exclusive
    int4 o;
    o.x = run; o.y = run + a.x; o.z = run + a.x + a.y; o.w = run + a.x + a.y + a.z;
    ((int4*)cnt)[t] = o;
    if (t == 255) tot[k] = wsum[255];
}

// 1 block: bucket bases from totals
__global__ void k_scan(const int* __restrict__ totT, const int* __restrict__ totC,
                       int* __restrict__ baseT, int* __restrict__ baseC) {
    __shared__ int s[NB];
    int t = threadIdx.x;   // NB threads
    int v = totT[t];
    s[t] = v; __syncthreads();
    for (int off = 1; off < NB; off <<= 1) {
        int x = (t >= off) ? s[t - off] : 0;
        __syncthreads();
        s[t] += x;
        __syncthreads();
    }
    baseT[t] = s[t] - v;
    if (t == NB - 1) baseT[NB] = s[t];
    __syncthreads();
    v = totC[t];
    s[t] = v; __syncthreads();
    for (int off = 1; off < NB; off <<= 1) {
        int x = (t >= off) ? s[t - off] : 0;
        __syncthreads();
        s[t] += x;
        __syncthreads();
    }
    baseC[t] = s[t] - v;
    if (t == NB - 1) baseC[NB] = s[t];
}

// PB blocks: scatter edges to bucket-sorted payload; cursors purely in LDS
__global__ void k_place(const int* __restrict__ trow, const int* __restrict__ tcol,
                        const int* __restrict__ crow, const int* __restrict__ ccol,
                        const float* __restrict__ ew, int E_,
                        const int* __restrict__ loffT, const int* __restrict__ loffC,
                        const int* __restrict__ baseT, const int* __restrict__ baseC,
                        unsigned* __restrict__ pT, unsigned long long* __restrict__ pC8) {
    __shared__ int curT[NB], curC[NB];
    int b = blockIdx.x;
    int chunk = (E_ + PB - 1) / PB;
    int s0 = b * chunk, s1 = min(E_, s0 + chunk);
    for (int k = threadIdx.x; k < NB; k += blockDim.x) {
        curT[k] = baseT[k] + loffT[k * PB + b];
        curC[k] = baseC[k] + loffC[k * PB + b];
    }
    __syncthreads();
    for (int j = s0 + threadIdx.x; j < s1; j += blockDim.x) {
        int tc = tcol[j];
        int k = tc / NPB;
        int pos = atomicAdd(&curT[k], 1);
        pT[pos] = ((unsigned)(tc - k * NPB) << LC_SHIFT) | (unsigned)trow[j];
        int cc = ccol[j];
        int k2 = cc / NPB;
        int p2 = atomicAdd(&curC[k2], 1);
        unsigned lo = ((unsigned)(cc - k2 * NPB) << LC_SHIFT) | (unsigned)crow[j];
        pC8[p2] = ((unsigned long long)__float_as_uint(ew[j]) << 32) | lo;
    }
}

// 2*NB blocks: per-bucket degree -> dis
__global__ void k_deg2(const unsigned* __restrict__ pT, const unsigned long long* __restrict__ pC8,
                       const int* __restrict__ baseT, const int* __restrict__ baseC,
                       float* __restrict__ dis_t, float* __restrict__ dis_c,
                       int nt, int nc) {
    __shared__ float acc[NPB];
    int b = blockIdx.x;
    bool car = b >= NB;
    int bk = car ? b - NB : b;
    const int* base = car ? baseC : baseT;
    int s0 = base[bk], s1 = base[bk + 1];
    for (int k = threadIdx.x; k < NPB; k += blockDim.x) acc[k] = 0.0f;
    __syncthreads();
    if (car) {
        for (int j = s0 + threadIdx.x; j < s1; j += blockDim.x) {
            unsigned long long v = pC8[j];
            atomicAdd(&acc[((unsigned)v) >> LC_SHIFT], __uint_as_float((unsigned)(v >> 32)));
        }
    } else {
        for (int j = s0 + threadIdx.x; j < s1; j += blockDim.x)
            atomicAdd(&acc[pT[j] >> LC_SHIFT], 1.0f);
    }
    __syncthreads();
    float* dis = car ? dis_c : dis_t;
    int ntot = car ? nc : nt;
    for (int n = threadIdx.x; n < NPB; n += blockDim.x) {
        int node = bk * NPB + n;
        if (node < ntot) dis[node] = rsqrtf(acc[n] + 1.0f);
    }
}

// 2*NB blocks: per-bucket aggregation -> s_t / y4
__global__ void k_agg(const unsigned* __restrict__ pT, const unsigned long long* __restrict__ pC8,
                      const int* __restrict__ baseT, const int* __restrict__ baseC,
                      const float* __restrict__ dis_t, const float* __restrict__ dis_c,
                      const float* __restrict__ x_car,
                      float* __restrict__ s_t, float4* __restrict__ y4,
                      int nt, int nc) {
    int b = blockIdx.x;
    if (b < NB) {
        __shared__ float sacc[NPB];
        int s0 = baseT[b], s1 = baseT[b + 1];
        for (int k = threadIdx.x; k < NPB; k += blockDim.x) sacc[k] = 0.0f;
        __syncthreads();
        for (int j = s0 + threadIdx.x; j < s1; j += blockDim.x) {
            unsigned v = pT[j];
            atomicAdd(&sacc[v >> LC_SHIFT], dis_t[v & ROW_MASK]);
        }
        __syncthreads();
        for (int n = threadIdx.x; n < NPB; n += blockDim.x) {
            int node = b * NPB + n;
            if (node < nt) {
                float d = dis_t[node];
                s_t[node] = fmaf(d, sacc[n], d * d);
            }
        }
    } else {
        int bk = b - NB;
        __shared__ float y[NPB * 5];   // stride 5: avoid stride-4 bank aliasing
        __shared__ float dcl[NPB];
        int s0 = baseC[bk], s1 = baseC[bk + 1];
        for (int k = threadIdx.x; k < NPB * 5; k += blockDim.x) y[k] = 0.0f;
        for (int k = threadIdx.x; k < NPB; k += blockDim.x) {
            int node = bk * NPB + k;
            dcl[k] = (node < nc) ? dis_c[node] : 0.0f;
        }
        __syncthreads();
        for (int j = s0 + threadIdx.x; j < s1; j += blockDim.x) {
            unsigned long long v = pC8[j];
            int r = (int)((unsigned)v & ROW_MASK);
            int lc = (int)(((unsigned)v) >> LC_SHIFT);
            float nrm = dis_c[r] * __uint_as_float((unsigned)(v >> 32)) * dcl[lc];
            const float* xr = &x_car[3 * r];
            atomicAdd(&y[lc * 5 + 0], nrm * xr[0]);
            atomicAdd(&y[lc * 5 + 1], nrm * xr[1]);
            atomicAdd(&y[lc * 5 + 2], nrm * xr[2]);
        }
        __syncthreads();
        for (int n = threadIdx.x; n < NPB; n += blockDim.x) {
            int node = bk * NPB + n;
            if (node < nc) {
                float d2 = dcl[n] * dcl[n];
                const float* xn = &x_car[3 * node];
                y4[node] = make_float4(fmaf(d2, xn[0], y[n * 5 + 0]),
                                       fmaf(d2, xn[1], y[n * 5 + 1]),
                                       fmaf(d2, xn[2], y[n * 5 + 2]), 1.0f);
            }
        }
    }
}

// ============ shared epilogue kernels ============

// G[a][b] = sum_h M[a,h]*M[b,h]*wlin[h], M rows = {W_truck, b_truck, Wc0, Wc1, Wc2, b_car}
__global__ void k_G(const float* __restrict__ Wt, const float* __restrict__ bt,
                    const float* __restrict__ Wc, const float* __restrict__ bc,
                    const float* __restrict__ wlin, float* __restrict__ G) {
    int l = threadIdx.x;  // 64 threads, 1 wave
    float acc[21];
#pragma unroll
    for (int k = 0; k < 21; k++) acc[k] = 0.0f;
    for (int h = l; h < 128; h += 64) {
        float m[6] = {Wt[h], bt[h], Wc[h], Wc[128 + h], Wc[256 + h], bc[h]};
        float w = wlin[h];
        int k = 0;
#pragma unroll
        for (int a = 0; a < 6; a++)
#pragma unroll
            for (int b = a; b < 6; b++)
                acc[k++] += m[a] * m[b] * w;
    }
    int k = 0;
#pragma unroll
    for (int a = 0; a < 6; a++)
#pragma unroll
        for (int b = a; b < 6; b++) {
            float v = acc[k++];
#pragma unroll
            for (int off = 32; off; off >>= 1) v += __shfl_down(v, off);
            if (l == 0) {
                G[a * 6 + b] = v;
                G[b * 6 + a] = v;
            }
        }
}

__device__ __forceinline__ void load_z(int i, const float* __restrict__ s_t,
                                       const float4* __restrict__ y4, float z[6]) {
    if (i < N_TRUCK) {
        z[0] = s_t[i]; z[1] = 1.0f; z[2] = 0.0f; z[3] = 0.0f; z[4] = 0.0f; z[5] = 0.0f;
    } else {
        float4 y = y4[i - N_TRUCK];
        z[0] = 0.0f; z[1] = 0.0f; z[2] = y.x; z[3] = y.y; z[4] = y.z; z[5] = 1.0f;
    }
}

__global__ void k_pairs(const int* __restrict__ src, const int* __restrict__ dst, int P_,
                        const float* __restrict__ s_t, const float4* __restrict__ y4,
                        const float* __restrict__ G, const float* __restrict__ b_lin,
                        float* __restrict__ out) {
    int p = blockIdx.x * blockDim.x + threadIdx.x;
    if (p >= P_) return;
    float zs[6], zd[6];
    load_z(src[p], s_t, y4, zs);
    load_z(dst[p], s_t, y4, zd);
    float acc = 0.0f;
#pragma unroll
    for (int a = 0; a < 6; a++) {
        float g = 0.0f;
#pragma unroll
        for (int b = 0; b < 6; b++) g = fmaf(G[a * 6 + b], zd[b], g);
        acc = fmaf(zs[a], g, acc);
    }
    out[p] = acc + b_lin[0];
}

// ============ fallback (atomic path) kernels ============

__global__ void k_deg(const int* __restrict__ tcol, const int* __restrict__ ccol,
                      const float* __restrict__ ew, int E_,
                      int* __restrict__ cnt_t, float* __restrict__ degw_c) {
    int i = blockIdx.x * blockDim.x + threadIdx.x;
    if (i >= E_) return;
    atomicAdd(&cnt_t[tcol[i]], 1);
    atomicAdd(&degw_c[ccol[i]], ew[i]);
}

__global__ void k_dis(const int* __restrict__ cnt_t, const float* __restrict__ degw_c,
                      float* __restrict__ dis_t, float* __restrict__ dis_c,
                      int nt, int nc) {
    int i = blockIdx.x * blockDim.x + threadIdx.x;
    if (i < nt) dis_t[i] = rsqrtf((float)cnt_t[i] + 1.0f);
    if (i < nc) dis_c[i] = rsqrtf(degw_c[i] + 1.0f);
}

__global__ void k_scat(const int* __restrict__ trow, const int* __restrict__ tcol,
                       const int* __restrict__ crow, const int* __restrict__ ccol,
                       const float* __restrict__ ew, int E_,
                       const float* __restrict__ dis_t, const float* __restrict__ dis_c,
                       const float* __restrict__ x_car,
                       float* __restrict__ sumdis, float* __restrict__ y4) {
    int i = blockIdx.x * blockDim.x + threadIdx.x;
    if (i >= E_) return;
    atomicAdd(&sumdis[tcol[i]], dis_t[trow[i]]);
    int r = crow[i], c = ccol[i];
    float nrm = dis_c[r] * ew[i] * dis_c[c];
    atomicAdd(&y4[c * 4 + 0], nrm * x_car[r * 3 + 0]);
    atomicAdd(&y4[c * 4 + 1], nrm * x_car[r * 3 + 1]);
    atomicAdd(&y4[c * 4 + 2], nrm * x_car[r * 3 + 2]);
}

__global__ void k_fin(int nt, int nc,
                      const float* __restrict__ dis_t, const float* __restrict__ sumdis,
                      float* __restrict__ s_t,
                      const float* __restrict__ dis_c, const float* __restrict__ x_car,
                      float* __restrict__ y4) {
    int i = blockIdx.x * blockDim.x + threadIdx.x;
    if (i < nt) {
        float d = dis_t[i];
        s_t[i] = d * sumdis[i] + d * d;
    }
    if (i < nc) {
        float d2 = dis_c[i] * dis_c[i];
        y4[i * 4 + 0] += d2 * x_car[i * 3 + 0];
        y4[i * 4 + 1] += d2 * x_car[i * 3 + 1];
        y4[i * 4 + 2] += d2 * x_car[i * 3 + 2];
        y4[i * 4 + 3] = 1.0f;
    }
}

// ============ launch ============

extern "C" void kernel_launch(void* const* d_in, const int* in_sizes, int n_in,
                              void* d_out, int out_size, void* d_ws, size_t ws_size,
                              hipStream_t stream) {
    const float* x_car  = (const float*)d_in[0];
    const int*   ei_t   = (const int*)d_in[1];
    const int*   ei_c   = (const int*)d_in[2];
    const float* ew_c   = (const float*)d_in[3];
    const int*   src    = (const int*)d_in[4];
    const int*   dst    = (const int*)d_in[5];
    const float* W_t    = (const float*)d_in[7];
    const float* b_t    = (const float*)d_in[8];
    const float* W_c    = (const float*)d_in[9];
    const float* b_c    = (const float*)d_in[10];
    const float* W_lin  = (const float*)d_in[11];
    const float* b_lin  = (const float*)d_in[12];
    float* out = (float*)d_out;

    const int NC = in_sizes[0] / 3;   // 100000
    const int E_ = in_sizes[1] / 2;   // 1600000
    const int P_ = in_sizes[4];       // 200000

    const int* trow = ei_t;  const int* tcol = ei_t + E_;
    const int* crow = ei_c;  const int* ccol = ei_c + E_;

    char* ws = (char*)d_ws;
    int gP = (P_ + BLK - 1) / BLK;

    if (ws_size >= WS_NEED) {
        int*      cntT  = (int*)(ws + 0);          // becomes loffT in place
        int*      cntC  = (int*)(ws + 1048576);    // becomes loffC in place
        float*    dis_t = (float*)(ws + 0);        // overlay, written post-place
        float*    dis_c = (float*)(ws + 400000);
        float*    s_t   = (float*)(ws + 800000);
        float*    y4    = (float*)(ws + 1200000);
        int*      baseT = (int*)(ws + 2800000);
        int*      baseC = (int*)(ws + 2801028);
        float*    G     = (float*)(ws + 2802056);
        int*      totT  = (int*)(ws + 2802200);
        int*      totC  = (int*)(ws + 2803224);
        unsigned* pT    = (unsigned*)(ws + 2804352);
        unsigned long long* pC8 = (unsigned long long*)(ws + 9204352);

        k_hist<<<PB, BLK, 0, stream>>>(tcol, ccol, E_, cntT, cntC);
        k_scanB<<<2 * NB, 256, 0, stream>>>(cntT, cntC, totT, totC);
        k_scan<<<1, NB, 0, stream>>>(totT, totC, baseT, baseC);
        k_place<<<PB, BLK, 0, stream>>>(trow, tcol, crow, ccol, ew_c, E_,
                                        cntT, cntC, baseT, baseC, pT, pC8);
        k_deg2<<<2 * NB, BLK, 0, stream>>>(pT, pC8, baseT, baseC, dis_t, dis_c, N_TRUCK, NC);
        k_G<<<1, 64, 0, stream>>>(W_t, b_t, W_c, b_c, W_lin, G);
        k_agg<<<2 * NB, BLK, 0, stream>>>(pT, pC8, baseT, baseC, dis_t, dis_c,
                                          x_car, s_t, (float4*)y4, N_TRUCK, NC);
        k_pairs<<<gP, BLK, 0, stream>>>(src, dst, P_, s_t, (const float4*)y4, G, b_lin, out);
    } else {
        // fallback: round-1 (passing) global-atomic path
        int*   cnt_t  = (int*)(ws + 0);
        float* sumdis = (float*)(ws + 400000);
        float* degw_c = (float*)(ws + 800000);
        float* y4     = (float*)(ws + 1200000);
        float* dis_t  = (float*)(ws + 2800000);
        float* dis_c  = (float*)(ws + 3200000);
        float* s_t    = (float*)(ws + 3600000);
        float* G      = (float*)(ws + 4000000);

        hipMemsetAsync(ws, 0, 2800000, stream);
        int gE = (E_ + BLK - 1) / BLK;
        int gN = ((N_TRUCK > NC ? N_TRUCK : NC) + BLK - 1) / BLK;
        k_deg<<<gE, BLK, 0, stream>>>(tcol, ccol, ew_c, E_, cnt_t, degw_c);
        k_dis<<<gN, BLK, 0, stream>>>(cnt_t, degw_c, dis_t, dis_c, N_TRUCK, NC);
        k_scat<<<gE, BLK, 0, stream>>>(trow, tcol, crow, ccol, ew_c, E_,
                                       dis_t, dis_c, x_car, sumdis, y4);
        k_fin<<<gN, BLK, 0, stream>>>(N_TRUCK, NC, dis_t, sumdis, s_t, dis_c, x_car, y4);
        k_G<<<1, 64, 0, stream>>>(W_t, b_t, W_c, b_c, W_lin, G);
        k_pairs<<<gP, BLK, 0, stream>>>(src, dst, P_, s_t, (const float4*)y4, G, b_lin, out);
    }
}

// Round 4
// 196.348 us; speedup vs baseline: 2.9541x; 1.0938x over previous
//
#include <hip/hip_runtime.h>

// Problem constants (fixed by reference file)
#define N_TRUCK 100000
#define BLK 256
#define NB 256           // buckets per graph
#define NPB 391          // nodes per bucket: ceil(100000/256)
#define PB 256           // placer/hist chunks
#define BLK_P 1024       // threads per place/hist/deg/agg block
#define ROW_MASK 0x1FFFFu
#define LC_SHIFT 17

// ---------------- ws layout (bytes) ----------------
// cntT i32[NB][PB] @ 0       (262144)   } dead after k_place (become loff in-place)
// cntC i32[NB][PB] @ 262144  (262144)   }
// overlay (written only after k_place):
//   dis_t @ 0        (400000)
//   dis_c @ 400000   (400000)
//   s_t   @ 800000   (400000)
//   y4    @ 1200000  (1600000)  ends 2800000
// baseT @ 2800000 (1028)   baseC @ 2801028 (1028)   G @ 2802056 (144)
// totT  @ 2802200 (1024)   totC  @ 2803224 (1024)
// pT  u32[E] @ 2804352 (6400000)
// pC8 u64[E] @ 9204352 (12800000)  ends 22004352
#define WS_NEED 22004352ULL

// ============ sort-path kernels ============

// PB blocks x BLK_P: per-chunk LDS histogram -> cnt[k][b]
__global__ void k_hist(const int* __restrict__ tcol, const int* __restrict__ ccol, int E_,
                       int* __restrict__ cntT, int* __restrict__ cntC) {
    __shared__ int hT[NB], hC[NB];
    int b = blockIdx.x;
    int chunk = (E_ + PB - 1) / PB;
    int s0 = b * chunk, s1 = min(E_, s0 + chunk);
    for (int k = threadIdx.x; k < NB; k += blockDim.x) { hT[k] = 0; hC[k] = 0; }
    __syncthreads();
    for (int j = s0 + threadIdx.x; j < s1; j += blockDim.x) {
        atomicAdd(&hT[tcol[j] / NPB], 1);
        atomicAdd(&hC[ccol[j] / NPB], 1);
    }
    __syncthreads();
    for (int k = threadIdx.x; k < NB; k += blockDim.x) {
        cntT[k * PB + b] = hT[k];
        cntC[k * PB + b] = hC[k];
    }
}

// 2*NB blocks x PB threads: exclusive scan of cnt[k][0..PB) IN PLACE, total -> tot[k]
__global__ void k_scanB(int* __restrict__ cntT, int* __restrict__ cntC,
                        int* __restrict__ totT, int* __restrict__ totC) {
    __shared__ int s[PB];
    int g = blockIdx.x;
    bool car = g >= NB;
    int k = car ? g - NB : g;
    int* cnt = (car ? cntC : cntT) + k * PB;
    int* tot = car ? totC : totT;
    int t = threadIdx.x;
    int v = cnt[t];
    s[t] = v;
    __syncthreads();
    for (int off = 1; off < PB; off <<= 1) {
        int x = (t >= off) ? s[t - off] : 0;
        __syncthreads();
        s[t] += x;
        __syncthreads();
    }
    cnt[t] = s[t] - v;          // exclusive
    if (t == PB - 1) tot[k] = s[t];
}

// 1 block: bucket bases from totals
__global__ void k_scan(const int* __restrict__ totT, const int* __restrict__ totC,
                       int* __restrict__ baseT, int* __restrict__ baseC) {
    __shared__ int s[NB];
    int t = threadIdx.x;   // NB threads
    int v = totT[t];
    s[t] = v; __syncthreads();
    for (int off = 1; off < NB; off <<= 1) {
        int x = (t >= off) ? s[t - off] : 0;
        __syncthreads();
        s[t] += x;
        __syncthreads();
    }
    baseT[t] = s[t] - v;
    if (t == NB - 1) baseT[NB] = s[t];
    __syncthreads();
    v = totC[t];
    s[t] = v; __syncthreads();
    for (int off = 1; off < NB; off <<= 1) {
        int x = (t >= off) ? s[t - off] : 0;
        __syncthreads();
        s[t] += x;
        __syncthreads();
    }
    baseC[t] = s[t] - v;
    if (t == NB - 1) baseC[NB] = s[t];
}

// PB blocks x BLK_P: scatter edges to bucket-sorted payload; cursors purely in LDS
__global__ void k_place(const int* __restrict__ trow, const int* __restrict__ tcol,
                        const int* __restrict__ crow, const int* __restrict__ ccol,
                        const float* __restrict__ ew, int E_,
                        const int* __restrict__ loffT, const int* __restrict__ loffC,
                        const int* __restrict__ baseT, const int* __restrict__ baseC,
                        unsigned* __restrict__ pT, unsigned long long* __restrict__ pC8) {
    __shared__ int curT[NB], curC[NB];
    int b = blockIdx.x;
    int chunk = (E_ + PB - 1) / PB;
    int s0 = b * chunk, s1 = min(E_, s0 + chunk);
    for (int k = threadIdx.x; k < NB; k += blockDim.x) {
        curT[k] = baseT[k] + loffT[k * PB + b];
        curC[k] = baseC[k] + loffC[k * PB + b];
    }
    __syncthreads();
    for (int j = s0 + threadIdx.x; j < s1; j += blockDim.x) {
        int tc = tcol[j];
        int k = tc / NPB;
        int pos = atomicAdd(&curT[k], 1);
        pT[pos] = ((unsigned)(tc - k * NPB) << LC_SHIFT) | (unsigned)trow[j];
        int cc = ccol[j];
        int k2 = cc / NPB;
        int p2 = atomicAdd(&curC[k2], 1);
        unsigned lo = ((unsigned)(cc - k2 * NPB) << LC_SHIFT) | (unsigned)crow[j];
        pC8[p2] = ((unsigned long long)__float_as_uint(ew[j]) << 32) | lo;
    }
}

// 2*NB blocks x BLK_P: per-bucket degree -> dis
__global__ void k_deg2(const unsigned* __restrict__ pT, const unsigned long long* __restrict__ pC8,
                       const int* __restrict__ baseT, const int* __restrict__ baseC,
                       float* __restrict__ dis_t, float* __restrict__ dis_c,
                       int nt, int nc) {
    __shared__ float acc[NPB];
    int b = blockIdx.x;
    bool car = b >= NB;
    int bk = car ? b - NB : b;
    const int* base = car ? baseC : baseT;
    int s0 = base[bk], s1 = base[bk + 1];
    for (int k = threadIdx.x; k < NPB; k += blockDim.x) acc[k] = 0.0f;
    __syncthreads();
    if (car) {
        for (int j = s0 + threadIdx.x; j < s1; j += blockDim.x) {
            unsigned long long v = pC8[j];
            atomicAdd(&acc[((unsigned)v) >> LC_SHIFT], __uint_as_float((unsigned)(v >> 32)));
        }
    } else {
        for (int j = s0 + threadIdx.x; j < s1; j += blockDim.x)
            atomicAdd(&acc[pT[j] >> LC_SHIFT], 1.0f);
    }
    __syncthreads();
    float* dis = car ? dis_c : dis_t;
    int ntot = car ? nc : nt;
    for (int n = threadIdx.x; n < NPB; n += blockDim.x) {
        int node = bk * NPB + n;
        if (node < ntot) dis[node] = rsqrtf(acc[n] + 1.0f);
    }
}

// 2*NB blocks x BLK_P: per-bucket aggregation -> s_t / y4
__global__ void k_agg(const unsigned* __restrict__ pT, const unsigned long long* __restrict__ pC8,
                      const int* __restrict__ baseT, const int* __restrict__ baseC,
                      const float* __restrict__ dis_t, const float* __restrict__ dis_c,
                      const float* __restrict__ x_car,
                      float* __restrict__ s_t, float4* __restrict__ y4,
                      int nt, int nc) {
    int b = blockIdx.x;
    if (b < NB) {
        __shared__ float sacc[NPB];
        int s0 = baseT[b], s1 = baseT[b + 1];
        for (int k = threadIdx.x; k < NPB; k += blockDim.x) sacc[k] = 0.0f;
        __syncthreads();
        for (int j = s0 + threadIdx.x; j < s1; j += blockDim.x) {
            unsigned v = pT[j];
            atomicAdd(&sacc[v >> LC_SHIFT], dis_t[v & ROW_MASK]);
        }
        __syncthreads();
        for (int n = threadIdx.x; n < NPB; n += blockDim.x) {
            int node = b * NPB + n;
            if (node < nt) {
                float d = dis_t[node];
                s_t[node] = fmaf(d, sacc[n], d * d);
            }
        }
    } else {
        int bk = b - NB;
        __shared__ float y[NPB * 5];   // stride 5: avoid stride-4 bank aliasing
        __shared__ float dcl[NPB];
        int s0 = baseC[bk], s1 = baseC[bk + 1];
        for (int k = threadIdx.x; k < NPB * 5; k += blockDim.x) y[k] = 0.0f;
        for (int k = threadIdx.x; k < NPB; k += blockDim.x) {
            int node = bk * NPB + k;
            dcl[k] = (node < nc) ? dis_c[node] : 0.0f;
        }
        __syncthreads();
        for (int j = s0 + threadIdx.x; j < s1; j += blockDim.x) {
            unsigned long long v = pC8[j];
            int r = (int)((unsigned)v & ROW_MASK);
            int lc = (int)(((unsigned)v) >> LC_SHIFT);
            float nrm = dis_c[r] * __uint_as_float((unsigned)(v >> 32)) * dcl[lc];
            const float* xr = &x_car[3 * r];
            atomicAdd(&y[lc * 5 + 0], nrm * xr[0]);
            atomicAdd(&y[lc * 5 + 1], nrm * xr[1]);
            atomicAdd(&y[lc * 5 + 2], nrm * xr[2]);
        }
        __syncthreads();
        for (int n = threadIdx.x; n < NPB; n += blockDim.x) {
            int node = bk * NPB + n;
            if (node < nc) {
                float d2 = dcl[n] * dcl[n];
                const float* xn = &x_car[3 * node];
                y4[node] = make_float4(fmaf(d2, xn[0], y[n * 5 + 0]),
                                       fmaf(d2, xn[1], y[n * 5 + 1]),
                                       fmaf(d2, xn[2], y[n * 5 + 2]), 1.0f);
            }
        }
    }
}

// ============ shared epilogue kernels ============

// G[a][b] = sum_h M[a,h]*M[b,h]*wlin[h], M rows = {W_truck, b_truck, Wc0, Wc1, Wc2, b_car}
__global__ void k_G(const float* __restrict__ Wt, const float* __restrict__ bt,
                    const float* __restrict__ Wc, const float* __restrict__ bc,
                    const float* __restrict__ wlin, float* __restrict__ G) {
    int l = threadIdx.x;  // 64 threads, 1 wave
    float acc[21];
#pragma unroll
    for (int k = 0; k < 21; k++) acc[k] = 0.0f;
    for (int h = l; h < 128; h += 64) {
        float m[6] = {Wt[h], bt[h], Wc[h], Wc[128 + h], Wc[256 + h], bc[h]};
        float w = wlin[h];
        int k = 0;
#pragma unroll
        for (int a = 0; a < 6; a++)
#pragma unroll
            for (int b = a; b < 6; b++)
                acc[k++] += m[a] * m[b] * w;
    }
    int k = 0;
#pragma unroll
    for (int a = 0; a < 6; a++)
#pragma unroll
        for (int b = a; b < 6; b++) {
            float v = acc[k++];
#pragma unroll
            for (int off = 32; off; off >>= 1) v += __shfl_down(v, off);
            if (l == 0) {
                G[a * 6 + b] = v;
                G[b * 6 + a] = v;
            }
        }
}

__device__ __forceinline__ void load_z(int i, const float* __restrict__ s_t,
                                       const float4* __restrict__ y4, float z[6]) {
    if (i < N_TRUCK) {
        z[0] = s_t[i]; z[1] = 1.0f; z[2] = 0.0f; z[3] = 0.0f; z[4] = 0.0f; z[5] = 0.0f;
    } else {
        float4 y = y4[i - N_TRUCK];
        z[0] = 0.0f; z[1] = 0.0f; z[2] = y.x; z[3] = y.y; z[4] = y.z; z[5] = 1.0f;
    }
}

__global__ void k_pairs(const int* __restrict__ src, const int* __restrict__ dst, int P_,
                        const float* __restrict__ s_t, const float4* __restrict__ y4,
                        const float* __restrict__ G, const float* __restrict__ b_lin,
                        float* __restrict__ out) {
    int p = blockIdx.x * blockDim.x + threadIdx.x;
    if (p >= P_) return;
    float zs[6], zd[6];
    load_z(src[p], s_t, y4, zs);
    load_z(dst[p], s_t, y4, zd);
    float acc = 0.0f;
#pragma unroll
    for (int a = 0; a < 6; a++) {
        float g = 0.0f;
#pragma unroll
        for (int b = 0; b < 6; b++) g = fmaf(G[a * 6 + b], zd[b], g);
        acc = fmaf(zs[a], g, acc);
    }
    out[p] = acc + b_lin[0];
}

// ============ fallback (atomic path) kernels ============

__global__ void k_deg(const int* __restrict__ tcol, const int* __restrict__ ccol,
                      const float* __restrict__ ew, int E_,
                      int* __restrict__ cnt_t, float* __restrict__ degw_c) {
    int i = blockIdx.x * blockDim.x + threadIdx.x;
    if (i >= E_) return;
    atomicAdd(&cnt_t[tcol[i]], 1);
    atomicAdd(&degw_c[ccol[i]], ew[i]);
}

__global__ void k_dis(const int* __restrict__ cnt_t, const float* __restrict__ degw_c,
                      float* __restrict__ dis_t, float* __restrict__ dis_c,
                      int nt, int nc) {
    int i = blockIdx.x * blockDim.x + threadIdx.x;
    if (i < nt) dis_t[i] = rsqrtf((float)cnt_t[i] + 1.0f);
    if (i < nc) dis_c[i] = rsqrtf(degw_c[i] + 1.0f);
}

__global__ void k_scat(const int* __restrict__ trow, const int* __restrict__ tcol,
                       const int* __restrict__ crow, const int* __restrict__ ccol,
                       const float* __restrict__ ew, int E_,
                       const float* __restrict__ dis_t, const float* __restrict__ dis_c,
                       const float* __restrict__ x_car,
                       float* __restrict__ sumdis, float* __restrict__ y4) {
    int i = blockIdx.x * blockDim.x + threadIdx.x;
    if (i >= E_) return;
    atomicAdd(&sumdis[tcol[i]], dis_t[trow[i]]);
    int r = crow[i], c = ccol[i];
    float nrm = dis_c[r] * ew[i] * dis_c[c];
    atomicAdd(&y4[c * 4 + 0], nrm * x_car[r * 3 + 0]);
    atomicAdd(&y4[c * 4 + 1], nrm * x_car[r * 3 + 1]);
    atomicAdd(&y4[c * 4 + 2], nrm * x_car[r * 3 + 2]);
}

__global__ void k_fin(int nt, int nc,
                      const float* __restrict__ dis_t, const float* __restrict__ sumdis,
                      float* __restrict__ s_t,
                      const float* __restrict__ dis_c, const float* __restrict__ x_car,
                      float* __restrict__ y4) {
    int i = blockIdx.x * blockDim.x + threadIdx.x;
    if (i < nt) {
        float d = dis_t[i];
        s_t[i] = d * sumdis[i] + d * d;
    }
    if (i < nc) {
        float d2 = dis_c[i] * dis_c[i];
        y4[i * 4 + 0] += d2 * x_car[i * 3 + 0];
        y4[i * 4 + 1] += d2 * x_car[i * 3 + 1];
        y4[i * 4 + 2] += d2 * x_car[i * 3 + 2];
        y4[i * 4 + 3] = 1.0f;
    }
}

// ============ launch ============

extern "C" void kernel_launch(void* const* d_in, const int* in_sizes, int n_in,
                              void* d_out, int out_size, void* d_ws, size_t ws_size,
                              hipStream_t stream) {
    const float* x_car  = (const float*)d_in[0];
    const int*   ei_t   = (const int*)d_in[1];
    const int*   ei_c   = (const int*)d_in[2];
    const float* ew_c   = (const float*)d_in[3];
    const int*   src    = (const int*)d_in[4];
    const int*   dst    = (const int*)d_in[5];
    const float* W_t    = (const float*)d_in[7];
    const float* b_t    = (const float*)d_in[8];
    const float* W_c    = (const float*)d_in[9];
    const float* b_c    = (const float*)d_in[10];
    const float* W_lin  = (const float*)d_in[11];
    const float* b_lin  = (const float*)d_in[12];
    float* out = (float*)d_out;

    const int NC = in_sizes[0] / 3;   // 100000
    const int E_ = in_sizes[1] / 2;   // 1600000
    const int P_ = in_sizes[4];       // 200000

    const int* trow = ei_t;  const int* tcol = ei_t + E_;
    const int* crow = ei_c;  const int* ccol = ei_c + E_;

    char* ws = (char*)d_ws;
    int gP = (P_ + BLK - 1) / BLK;

    if (ws_size >= WS_NEED) {
        int*      cntT  = (int*)(ws + 0);          // becomes loffT in place
        int*      cntC  = (int*)(ws + 262144);     // becomes loffC in place
        float*    dis_t = (float*)(ws + 0);        // overlay, written post-place
        float*    dis_c = (float*)(ws + 400000);
        float*    s_t   = (float*)(ws + 800000);
        float*    y4    = (float*)(ws + 1200000);
        int*      baseT = (int*)(ws + 2800000);
        int*      baseC = (int*)(ws + 2801028);
        float*    G     = (float*)(ws + 2802056);
        int*      totT  = (int*)(ws + 2802200);
        int*      totC  = (int*)(ws + 2803224);
        unsigned* pT    = (unsigned*)(ws + 2804352);
        unsigned long long* pC8 = (unsigned long long*)(ws + 9204352);

        k_hist<<<PB, BLK_P, 0, stream>>>(tcol, ccol, E_, cntT, cntC);
        k_scanB<<<2 * NB, PB, 0, stream>>>(cntT, cntC, totT, totC);
        k_scan<<<1, NB, 0, stream>>>(totT, totC, baseT, baseC);
        k_place<<<PB, BLK_P, 0, stream>>>(trow, tcol, crow, ccol, ew_c, E_,
                                          cntT, cntC, baseT, baseC, pT, pC8);
        k_deg2<<<2 * NB, BLK_P, 0, stream>>>(pT, pC8, baseT, baseC, dis_t, dis_c, N_TRUCK, NC);
        k_G<<<1, 64, 0, stream>>>(W_t, b_t, W_c, b_c, W_lin, G);
        k_agg<<<2 * NB, BLK_P, 0, stream>>>(pT, pC8, baseT, baseC, dis_t, dis_c,
                                            x_car, s_t, (float4*)y4, N_TRUCK, NC);
        k_pairs<<<gP, BLK, 0, stream>>>(src, dst, P_, s_t, (const float4*)y4, G, b_lin, out);
    } else {
        // fallback: round-1 (passing) global-atomic path
        int*   cnt_t  = (int*)(ws + 0);
        float* sumdis = (float*)(ws + 400000);
        float* degw_c = (float*)(ws + 800000);
        float* y4     = (float*)(ws + 1200000);
        float* dis_t  = (float*)(ws + 2800000);
        float* dis_c  = (float*)(ws + 3200000);
        float* s_t    = (float*)(ws + 3600000);
        float* G      = (float*)(ws + 4000000);

        hipMemsetAsync(ws, 0, 2800000, stream);
        int gE = (E_ + BLK - 1) / BLK;
        int gN = ((N_TRUCK > NC ? N_TRUCK : NC) + BLK - 1) / BLK;
        k_deg<<<gE, BLK, 0, stream>>>(tcol, ccol, ew_c, E_, cnt_t, degw_c);
        k_dis<<<gN, BLK, 0, stream>>>(cnt_t, degw_c, dis_t, dis_c, N_TRUCK, NC);
        k_scat<<<gE, BLK, 0, stream>>>(trow, tcol, crow, ccol, ew_c, E_,
                                       dis_t, dis_c, x_car, sumdis, y4);
        k_fin<<<gN, BLK, 0, stream>>>(N_TRUCK, NC, dis_t, sumdis, s_t, dis_c, x_car, y4);
        k_G<<<1, 64, 0, stream>>>(W_t, b_t, W_c, b_c, W_lin, G);
        k_pairs<<<gP, BLK, 0, stream>>>(src, dst, P_, s_t, (const float4*)y4, G, b_lin, out);
    }
}